// Round 1
// baseline (1024.333 us; speedup 1.0000x reference)
//
#include <hip/hip_runtime.h>
#include <hip/hip_bf16.h>
#include <math.h>

// Transformer block: rmsnorm -> QKV (GQA 16q/4kv, hd=128) -> rope -> causal flash attn
// -> Wo + residual -> rmsnorm -> SwiGLU MLP -> residual.
// All GEMMs: bf16 MFMA 16x16x32, 128x128 tile, BK=64, global_load_lds(16B) staging.
// B=1, S=2048, HIDDEN=2048, INTER=8192. fp32 in/out; bf16 internal compute.

#define HIDDENC 2048
#define SLEN    2048
#define NHEADS  16
#define NKV     4
#define HD      128
#define INTERC  8192

typedef __attribute__((ext_vector_type(8))) short bf16x8;   // 8 x bf16 (4 VGPRs)
typedef __attribute__((ext_vector_type(4))) float f32x4;
typedef __hip_bfloat16 bf16;

__device__ __forceinline__ void gld_lds16(const void* g, void* l) {
    // async global->LDS, 16B per lane; LDS dest = wave-uniform base + lane*16
    __builtin_amdgcn_global_load_lds((const __attribute__((address_space(1))) void*)g,
                                     (__attribute__((address_space(3))) void*)l, 16, 0, 0);
}

__device__ __forceinline__ unsigned short bf_bits(float x) {
    bf16 t = __float2bfloat16(x);
    return *(unsigned short*)&t;
}
__device__ __forceinline__ float bits_f(short s) {
    bf16 b = *(bf16*)&s;
    return __bfloat162float(b);
}

// ---------------- GEMM: C[M][N] = A[M][K] @ B[N][K]^T  (both K-major) ---------------
// EPI=0: write bf16 C.  EPI=1: write fp32 C = acc + R (residual, fp32).
template <int EPI>
__global__ __launch_bounds__(256) void gemm_bt(const bf16* __restrict__ A,
                                               const bf16* __restrict__ B,
                                               void* __restrict__ Cout,
                                               const float* __restrict__ R,
                                               int M, int N, int K) {
    constexpr int BM = 128, BN = 128, BK = 64;
    __shared__ bf16 As[BM * BK];
    __shared__ bf16 Bs[BN * BK];
    const int tid  = threadIdx.x;
    const int wave = tid >> 6;
    const int lane = tid & 63;
    const int wm = wave >> 1, wn = wave & 1;        // 2x2 waves, 64x64 each
    const long m0 = (long)blockIdx.y * BM;
    const long n0 = (long)blockIdx.x * BN;

    // staging: wave w, iter t covers 8 rows (1KB LDS); lane l -> row +l/8, col (l%8)*8
    const int srow = wave * 8 + (lane >> 3);
    const int scol = (lane & 7) * 8;
    const bf16* Ag = A + (m0 + srow) * (long)K + scol;
    const bf16* Bg = B + (n0 + srow) * (long)K + scol;
    bf16* Asw = &As[(wave * 8) * BK];
    bf16* Bsw = &Bs[(wave * 8) * BK];

    f32x4 acc[4][4] = {};
    const int row = lane & 15;
    const int kq  = (lane >> 4) * 8;

    for (int k0 = 0; k0 < K; k0 += BK) {
#pragma unroll
        for (int t = 0; t < 4; t++) {
            gld_lds16(Ag + (long)(t * 32) * K + k0, Asw + t * 32 * BK);
            gld_lds16(Bg + (long)(t * 32) * K + k0, Bsw + t * 32 * BK);
        }
        __syncthreads();
#pragma unroll
        for (int kk = 0; kk < BK; kk += 32) {
            bf16x8 af[4], bfr[4];
#pragma unroll
            for (int i = 0; i < 4; i++)
                af[i] = *(const bf16x8*)&As[(wm * 64 + i * 16 + row) * BK + kk + kq];
#pragma unroll
            for (int j = 0; j < 4; j++)
                bfr[j] = *(const bf16x8*)&Bs[(wn * 64 + j * 16 + row) * BK + kk + kq];
#pragma unroll
            for (int i = 0; i < 4; i++)
#pragma unroll
                for (int j = 0; j < 4; j++)
                    acc[i][j] = __builtin_amdgcn_mfma_f32_16x16x32_bf16(af[i], bfr[j], acc[i][j], 0, 0, 0);
        }
        __syncthreads();
    }

    const int quad = lane >> 4;
#pragma unroll
    for (int i = 0; i < 4; i++)
#pragma unroll
        for (int j = 0; j < 4; j++)
#pragma unroll
            for (int r = 0; r < 4; r++) {
                long rr = m0 + wm * 64 + i * 16 + quad * 4 + r;   // C/D: row = quad*4+reg
                long cc = n0 + wn * 64 + j * 16 + (lane & 15);    //      col = lane&15
                float v = acc[i][j][r];
                if (EPI == 0) {
                    ((bf16*)Cout)[rr * N + cc] = __float2bfloat16(v);
                } else {
                    ((float*)Cout)[rr * N + cc] = v + R[rr * N + cc];
                }
            }
}

// ---------------- RMSNorm: one block per row, fp32 in -> bf16 out -------------------
__global__ __launch_bounds__(256) void rmsnorm_kernel(const float* __restrict__ x,
                                                      const float* __restrict__ w,
                                                      bf16* __restrict__ out) {
    const int row = blockIdx.x;
    const int tid = threadIdx.x;
    const float* xr = x + (long)row * HIDDENC;
    float4 a = *(const float4*)&xr[tid * 8];
    float4 b = *(const float4*)&xr[tid * 8 + 4];
    float ss = a.x*a.x + a.y*a.y + a.z*a.z + a.w*a.w + b.x*b.x + b.y*b.y + b.z*b.z + b.w*b.w;
#pragma unroll
    for (int d = 1; d < 64; d <<= 1) ss += __shfl_xor(ss, d, 64);
    __shared__ float wsum[4];
    if ((tid & 63) == 0) wsum[tid >> 6] = ss;
    __syncthreads();
    ss = wsum[0] + wsum[1] + wsum[2] + wsum[3];
    float sc = rsqrtf(ss * (1.0f / HIDDENC) + 1e-6f);
    float4 wa = *(const float4*)&w[tid * 8];
    float4 wb = *(const float4*)&w[tid * 8 + 4];
    float vals[8] = {a.x*wa.x, a.y*wa.y, a.z*wa.z, a.w*wa.w,
                     b.x*wb.x, b.y*wb.y, b.z*wb.z, b.w*wb.w};
    union { bf16x8 v; unsigned short u[8]; } pk;
#pragma unroll
    for (int e = 0; e < 8; e++) pk.u[e] = bf_bits(vals[e] * sc);
    *(bf16x8*)&out[(long)row * HIDDENC + tid * 8] = pk.v;
}

// ---------------- fp32 -> bf16 convert (weights) ------------------------------------
__global__ __launch_bounds__(256) void cvt_kernel(const float* __restrict__ in,
                                                  bf16* __restrict__ out, long n) {
    long idx = ((long)blockIdx.x * 256 + threadIdx.x) * 8;
    if (idx >= n) return;
    float4 a = *(const float4*)&in[idx];
    float4 b = *(const float4*)&in[idx + 4];
    float vals[8] = {a.x, a.y, a.z, a.w, b.x, b.y, b.z, b.w};
    union { bf16x8 v; unsigned short u[8]; } pk;
#pragma unroll
    for (int e = 0; e < 8; e++) pk.u[e] = bf_bits(vals[e]);
    *(bf16x8*)&out[idx] = pk.v;
}

// ---------------- RoPE in-place on bf16 [S][rowstride], heads at col h*HD -----------
__global__ __launch_bounds__(256) void rope_kernel(bf16* __restrict__ x,
                                                   const int* __restrict__ pos,
                                                   int nheads, int rowstride) {
    long gid = (long)blockIdx.x * 256 + threadIdx.x;
    int i = gid & 63;
    long t = gid >> 6;
    int h = (int)(t % nheads);
    long s = t / nheads;
    if (s >= SLEN) return;
    float inv = __expf(-(float)i * 0.14391156516779195f);   // ln(10000)/64
    float f = (float)pos[s] * inv;
    float sn, c;
    sincosf(f, &sn, &c);
    bf16* p = x + s * (long)rowstride + h * HD + i;
    float x1 = __bfloat162float(p[0]);
    float x2 = __bfloat162float(p[64]);
    p[0]  = __float2bfloat16(x1 * c - x2 * sn);
    p[64] = __float2bfloat16(x2 * c + x1 * sn);
}

// ---------------- causal flash attention, MFMA, GQA ---------------------------------
// grid (16 qtiles, 16 heads), 256 thr. Q-tile 128 rows (32/wave), K-tiles of 64 keys.
__global__ __launch_bounds__(256) void flash_attn(const bf16* __restrict__ Q,   // [S][2048]
                                                  const bf16* __restrict__ Kb,  // [S][512]
                                                  const bf16* __restrict__ Vb,  // [S][512]
                                                  bf16* __restrict__ Ctx) {     // [S][2048]
    constexpr int BQ = 128, BKEY = 64, PSTR = 72;   // PSTR: padded key stride (bank spread)
    __shared__ bf16 Ks[BKEY * HD];                  // [64 keys][128 d], unpadded (gld_lds)
    __shared__ bf16 VT[HD * PSTR];                  // [128 d][64 keys + pad]
    __shared__ bf16 Ps[4 * 32 * PSTR];              // per-wave P [32 q][64 keys + pad]
    const int qi = blockIdx.x;
    const int h  = blockIdx.y;
    const int kvh = h >> 2;                          // GQA: 4 q-heads per kv-head
    const int tid = threadIdx.x;
    const int wave = tid >> 6, lane = tid & 63;
    const int quad = lane >> 4, lrow = lane & 15;

    // resident Q fragments (A-operand layout: m=lane&15, k=quad*8+j), loaded from global
    bf16x8 qf[2][4];
    const long qrow0 = (long)qi * BQ + wave * 32;
#pragma unroll
    for (int i = 0; i < 2; i++)
#pragma unroll
        for (int kk = 0; kk < 4; kk++)
            qf[i][kk] = *(const bf16x8*)&Q[(qrow0 + i * 16 + lrow) * (NHEADS * HD) + h * HD + kk * 32 + quad * 8];

    f32x4 o[2][8] = {};
    float mrow[2][4], lsum[2][4];
#pragma unroll
    for (int i = 0; i < 2; i++)
#pragma unroll
        for (int r = 0; r < 4; r++) { mrow[i][r] = -1e30f; lsum[i][r] = 0.0f; }

    const int nkt = 2 * qi + 2;                      // causal: keys < (qi+1)*128
    const float scale = 0.08838834764831845f;        // 1/sqrt(128)

    for (int kt = 0; kt < nkt; kt++) {
        __syncthreads();                             // protect Ks/VT from prior reads
        // stage K tile [64][128] via global_load_lds: wave w iter t -> 4 rows
#pragma unroll
        for (int t = 0; t < 4; t++) {
            int qc  = t * 4 + wave;                  // 0..15, wave-uniform
            int key = qc * 4 + (lane >> 4);
            int dcol = (lane & 15) * 8;
            gld_lds16(&Kb[((long)kt * BKEY + key) * (NKV * HD) + kvh * HD + dcol],
                      &Ks[(qc * 4) * HD]);
        }
        // stage V^T [d][key] via VGPR transpose (padded stride)
#pragma unroll
        for (int t = 0; t < 4; t++) {
            int c = t * 256 + tid;
            int key = c >> 4, dc = c & 15;
            bf16x8 vv = *(const bf16x8*)&Vb[((long)kt * BKEY + key) * (NKV * HD) + kvh * HD + dc * 8];
            const short* vs = (const short*)&vv;
#pragma unroll
            for (int e = 0; e < 8; e++)
                *(short*)&VT[(dc * 8 + e) * PSTR + key] = vs[e];
        }
        __syncthreads();

        // S = Q K^T (scaled later): tiles i(2) x j(4), contraction d=128 (4 kk-steps)
        f32x4 sacc[2][4] = {};
#pragma unroll
        for (int kk = 0; kk < 4; kk++) {
            bf16x8 kb[4];
#pragma unroll
            for (int j = 0; j < 4; j++)
                kb[j] = *(const bf16x8*)&Ks[(j * 16 + lrow) * HD + kk * 32 + quad * 8];
#pragma unroll
            for (int i = 0; i < 2; i++)
#pragma unroll
                for (int j = 0; j < 4; j++)
                    sacc[i][j] = __builtin_amdgcn_mfma_f32_16x16x32_bf16(qf[i][kk], kb[j], sacc[i][j], 0, 0, 0);
        }

        // scale + causal mask (only tiles crossing the diagonal)
        const bool diag = (kt >= 2 * qi);
#pragma unroll
        for (int i = 0; i < 2; i++)
#pragma unroll
            for (int j = 0; j < 4; j++)
#pragma unroll
                for (int r = 0; r < 4; r++) {
                    float v = sacc[i][j][r] * scale;
                    if (diag) {
                        long rowg = qrow0 + i * 16 + quad * 4 + r;
                        long colg = (long)kt * BKEY + j * 16 + lrow;
                        if (colg > rowg) v = -1e30f;
                    }
                    sacc[i][j][r] = v;
                }

        // online softmax per q-row (rows live on lanes with same quad: reduce low 4 bits)
        float alpha[2][4];
#pragma unroll
        for (int i = 0; i < 2; i++)
#pragma unroll
            for (int r = 0; r < 4; r++) {
                float mx = sacc[i][0][r];
#pragma unroll
                for (int j = 1; j < 4; j++) mx = fmaxf(mx, sacc[i][j][r]);
#pragma unroll
                for (int d = 1; d < 16; d <<= 1) mx = fmaxf(mx, __shfl_xor(mx, d, 16));
                float mnew = fmaxf(mrow[i][r], mx);
                float a = __expf(mrow[i][r] - mnew);
                mrow[i][r] = mnew;
                alpha[i][r] = a;
                float rs = 0.0f;
#pragma unroll
                for (int j = 0; j < 4; j++) {
                    float p = __expf(sacc[i][j][r] - mnew);
                    sacc[i][j][r] = p;
                    rs += p;
                }
#pragma unroll
                for (int d = 1; d < 16; d <<= 1) rs += __shfl_xor(rs, d, 16);
                lsum[i][r] = lsum[i][r] * a + rs;
            }

        // rescale O
#pragma unroll
        for (int i = 0; i < 2; i++)
#pragma unroll
            for (int dj = 0; dj < 8; dj++)
#pragma unroll
                for (int r = 0; r < 4; r++) o[i][dj][r] *= alpha[i][r];

        // P (C-layout) -> per-wave LDS -> A-operand fragments
        bf16* Pw = &Ps[wave * 32 * PSTR];
#pragma unroll
        for (int i = 0; i < 2; i++)
#pragma unroll
            for (int j = 0; j < 4; j++)
#pragma unroll
                for (int r = 0; r < 4; r++)
                    Pw[(i * 16 + quad * 4 + r) * PSTR + j * 16 + lrow] = __float2bfloat16(sacc[i][j][r]);
        __asm__ volatile("s_waitcnt lgkmcnt(0)" ::: "memory");   // same-wave write->read

        // O += P V  (contraction keys=64: 2 kk-steps)
#pragma unroll
        for (int kk = 0; kk < 2; kk++) {
            bf16x8 pf[2];
#pragma unroll
            for (int i = 0; i < 2; i++)
                pf[i] = *(const bf16x8*)&Pw[(i * 16 + lrow) * PSTR + kk * 32 + quad * 8];
#pragma unroll
            for (int dj = 0; dj < 8; dj++) {
                bf16x8 vb = *(const bf16x8*)&VT[(dj * 16 + lrow) * PSTR + kk * 32 + quad * 8];
#pragma unroll
                for (int i = 0; i < 2; i++)
                    o[i][dj] = __builtin_amdgcn_mfma_f32_16x16x32_bf16(pf[i], vb, o[i][dj], 0, 0, 0);
            }
        }
    }

    // epilogue: ctx[s][h*128 + d] = O / lsum
#pragma unroll
    for (int i = 0; i < 2; i++)
#pragma unroll
        for (int dj = 0; dj < 8; dj++)
#pragma unroll
            for (int r = 0; r < 4; r++) {
                long rowg = qrow0 + i * 16 + quad * 4 + r;
                long col  = (long)h * HD + dj * 16 + lrow;
                Ctx[rowg * (NHEADS * HD) + col] = __float2bfloat16(o[i][dj][r] / lsum[i][r]);
            }
}

// ---------------- SwiGLU elementwise: act = silu(gate) * up (bf16) ------------------
__global__ __launch_bounds__(256) void silu_mul_kernel(const bf16* __restrict__ g,
                                                       const bf16* __restrict__ u,
                                                       bf16* __restrict__ out, long n) {
    long idx = ((long)blockIdx.x * 256 + threadIdx.x) * 8;
    if (idx >= n) return;
    bf16x8 gv = *(const bf16x8*)&g[idx];
    bf16x8 uv = *(const bf16x8*)&u[idx];
    union { bf16x8 v; unsigned short w[8]; } pk;
#pragma unroll
    for (int e = 0; e < 8; e++) {
        float gf = bits_f(gv[e]);
        float uf = bits_f(uv[e]);
        float s = gf / (1.0f + __expf(-gf));
        pk.w[e] = bf_bits(s * uf);
    }
    *(bf16x8*)&out[idx] = pk.v;
}

// ------------------------------------------------------------------------------------
extern "C" void kernel_launch(void* const* d_in, const int* in_sizes, int n_in,
                              void* d_out, int out_size, void* d_ws, size_t ws_size,
                              hipStream_t stream) {
    const float* hidden = (const float*)d_in[0];
    // d_in[1] attention_mask: exactly causal -1e9; implemented as hard causal mask.
    const int*   pos    = (const int*)d_in[2];
    const float* n1w    = (const float*)d_in[3];
    const float* n2w    = (const float*)d_in[4];
    const float* Wq     = (const float*)d_in[5];
    const float* Wk     = (const float*)d_in[6];
    const float* Wv     = (const float*)d_in[7];
    const float* Wo     = (const float*)d_in[8];
    const float* Wg     = (const float*)d_in[9];
    const float* Wu     = (const float*)d_in[10];
    const float* Wd     = (const float*)d_in[11];
    float* out = (float*)d_out;

    char* ws = (char*)d_ws;
    const size_t MB = 1ull << 20;
    // Phase A (attention):                        Phase B (MLP) reuses 8..40MB:
    bf16* h    = (bf16*)(ws + 0);        // 8 MB   (also h2)
    bf16* q    = (bf16*)(ws + 8  * MB);  // 8 MB
    bf16* k    = (bf16*)(ws + 16 * MB);  // 2 MB
    bf16* v    = (bf16*)(ws + 18 * MB);  // 2 MB
    bf16* ctx  = (bf16*)(ws + 20 * MB);  // 8 MB
    bf16* wqkv = (bf16*)(ws + 28 * MB);  // 12 MB: wq(8)+wk(2)+wv(2); reused for wo(8)
    bf16* gate = (bf16*)(ws + 8  * MB);  // 32 MB  (overlaps q..wqkv, phase B only)
    bf16* up   = (bf16*)(ws + 40 * MB);  // 32 MB
    bf16* wg   = (bf16*)(ws + 72 * MB);  // 32 MB  (reused for wdown)
    bf16* wu   = (bf16*)(ws + 104 * MB); // 32 MB  -> total 136 MB
    bf16* wqb = wqkv;
    bf16* wkb = wqkv + 4 * 1024 * 1024;
    bf16* wvb = wkb + 1024 * 1024;
    bf16* wob = wqkv;

    // 1) rmsnorm1 -> h (bf16)
    rmsnorm_kernel<<<dim3(2048), dim3(256), 0, stream>>>(hidden, n1w, h);
    // 2) convert attention weights
    cvt_kernel<<<dim3(2048), dim3(256), 0, stream>>>(Wq, wqb, 2048L * 2048);
    cvt_kernel<<<dim3(512),  dim3(256), 0, stream>>>(Wk, wkb, 512L * 2048);
    cvt_kernel<<<dim3(512),  dim3(256), 0, stream>>>(Wv, wvb, 512L * 2048);
    // 3) q/k/v projections
    gemm_bt<0><<<dim3(16, 16), dim3(256), 0, stream>>>(h, wqb, q, nullptr, 2048, 2048, 2048);
    gemm_bt<0><<<dim3(4, 16),  dim3(256), 0, stream>>>(h, wkb, k, nullptr, 2048, 512, 2048);
    gemm_bt<0><<<dim3(4, 16),  dim3(256), 0, stream>>>(h, wvb, v, nullptr, 2048, 512, 2048);
    // 4) rope (in-place, bf16)
    rope_kernel<<<dim3(8192), dim3(256), 0, stream>>>(q, pos, NHEADS, NHEADS * HD);
    rope_kernel<<<dim3(2048), dim3(256), 0, stream>>>(k, pos, NKV, NKV * HD);
    // 5) causal flash attention -> ctx
    flash_attn<<<dim3(16, 16), dim3(256), 0, stream>>>(q, k, v, ctx);
    // 6) output projection + residual -> out (fp32)
    cvt_kernel<<<dim3(2048), dim3(256), 0, stream>>>(Wo, wob, 2048L * 2048);
    gemm_bt<1><<<dim3(16, 16), dim3(256), 0, stream>>>(ctx, wob, out, hidden, 2048, 2048, 2048);
    // 7) rmsnorm2 -> h2 (bf16, reuses h)
    rmsnorm_kernel<<<dim3(2048), dim3(256), 0, stream>>>(out, n2w, h);
    // 8) MLP
    cvt_kernel<<<dim3(8192), dim3(256), 0, stream>>>(Wg, wg, 8192L * 2048);
    cvt_kernel<<<dim3(8192), dim3(256), 0, stream>>>(Wu, wu, 8192L * 2048);
    gemm_bt<0><<<dim3(64, 16), dim3(256), 0, stream>>>(h, wg, gate, nullptr, 2048, 8192, 2048);
    gemm_bt<0><<<dim3(64, 16), dim3(256), 0, stream>>>(h, wu, up,   nullptr, 2048, 8192, 2048);
    silu_mul_kernel<<<dim3(8192), dim3(256), 0, stream>>>(gate, up, gate, 2048L * 8192);
    cvt_kernel<<<dim3(8192), dim3(256), 0, stream>>>(Wd, wg, 2048L * 8192);   // wdown into wg slot
    // 9) down-proj + residual (reads out=x, writes out), K=8192
    gemm_bt<1><<<dim3(16, 16), dim3(256), 0, stream>>>(gate, wg, out, out, 2048, 2048, 8192);
    (void)in_sizes; (void)n_in; (void)out_size; (void)ws_size;
}

// Round 2
// 916.278 us; speedup vs baseline: 1.1179x; 1.1179x over previous
//
#include <hip/hip_runtime.h>
#include <hip/hip_bf16.h>
#include <math.h>

// Transformer block: rmsnorm -> fused QKV GEMM -> rope -> causal flash attn (v2)
// -> Wo + residual -> rmsnorm -> SwiGLU MLP -> split-K down-proj + residual.
// B=1, S=2048, HIDDEN=2048, INTER=8192. fp32 in/out; bf16 internal compute.

#define HIDDENC 2048
#define SLEN    2048
#define NHEADS  16
#define NKV     4
#define HD      128
#define INTERC  8192

typedef __attribute__((ext_vector_type(8))) short bf16x8;   // 8 x bf16 (4 VGPRs)
typedef __attribute__((ext_vector_type(4))) float f32x4;
typedef __hip_bfloat16 bf16;

__device__ __forceinline__ void gld_lds16(const void* g, void* l) {
    __builtin_amdgcn_global_load_lds((const __attribute__((address_space(1))) void*)g,
                                     (__attribute__((address_space(3))) void*)l, 16, 0, 0);
}

__device__ __forceinline__ unsigned short bf_bits(float x) {
    bf16 t = __float2bfloat16(x);
    return *(unsigned short*)&t;
}
__device__ __forceinline__ float bits_f(short s) {
    bf16 b = *(bf16*)&s;
    return __bfloat162float(b);
}

// ---------------- GEMM: C[M][N] = A[M][K'] @ B[N][K']^T, row stride lda -------------
// EPI=0: bf16 C.  EPI=1: fp32 C = acc + R.  EPI=2: fp32 partial at Cout + z*M*N
// (split-K: blockIdx.z = z selects k-range [z*K, (z+1)*K) within stride lda).
template <int EPI>
__global__ __launch_bounds__(256) void gemm_bt(const bf16* __restrict__ A,
                                               const bf16* __restrict__ B,
                                               void* __restrict__ Cout,
                                               const float* __restrict__ R,
                                               int M, int N, int K, int lda) {
    constexpr int BM = 128, BN = 128, BK = 64;
    __shared__ bf16 As[BM * BK];
    __shared__ bf16 Bs[BN * BK];
    const int tid  = threadIdx.x;
    const int wave = tid >> 6;
    const int lane = tid & 63;
    const int wm = wave >> 1, wn = wave & 1;        // 2x2 waves, 64x64 each
    const long m0 = (long)blockIdx.y * BM;
    const long n0 = (long)blockIdx.x * BN;
    const long kofs = (long)blockIdx.z * K;

    const int srow = wave * 8 + (lane >> 3);
    const int scol = (lane & 7) * 8;
    const bf16* Ag = A + (m0 + srow) * (long)lda + scol + kofs;
    const bf16* Bg = B + (n0 + srow) * (long)lda + scol + kofs;
    bf16* Asw = &As[(wave * 8) * BK];
    bf16* Bsw = &Bs[(wave * 8) * BK];

    f32x4 acc[4][4] = {};
    const int row = lane & 15;
    const int kq  = (lane >> 4) * 8;

    for (int k0 = 0; k0 < K; k0 += BK) {
#pragma unroll
        for (int t = 0; t < 4; t++) {
            gld_lds16(Ag + (long)(t * 32) * lda + k0, Asw + t * 32 * BK);
            gld_lds16(Bg + (long)(t * 32) * lda + k0, Bsw + t * 32 * BK);
        }
        __syncthreads();
#pragma unroll
        for (int kk = 0; kk < BK; kk += 32) {
            bf16x8 af[4], bfr[4];
#pragma unroll
            for (int i = 0; i < 4; i++)
                af[i] = *(const bf16x8*)&As[(wm * 64 + i * 16 + row) * BK + kk + kq];
#pragma unroll
            for (int j = 0; j < 4; j++)
                bfr[j] = *(const bf16x8*)&Bs[(wn * 64 + j * 16 + row) * BK + kk + kq];
#pragma unroll
            for (int i = 0; i < 4; i++)
#pragma unroll
                for (int j = 0; j < 4; j++)
                    acc[i][j] = __builtin_amdgcn_mfma_f32_16x16x32_bf16(af[i], bfr[j], acc[i][j], 0, 0, 0);
        }
        __syncthreads();
    }

    const int quad = lane >> 4;
#pragma unroll
    for (int i = 0; i < 4; i++)
#pragma unroll
        for (int j = 0; j < 4; j++)
#pragma unroll
            for (int r = 0; r < 4; r++) {
                long rr = m0 + wm * 64 + i * 16 + quad * 4 + r;   // C/D: row = quad*4+reg
                long cc = n0 + wn * 64 + j * 16 + (lane & 15);    //      col = lane&15
                float v = acc[i][j][r];
                if (EPI == 0) {
                    ((bf16*)Cout)[rr * N + cc] = __float2bfloat16(v);
                } else if (EPI == 1) {
                    ((float*)Cout)[rr * N + cc] = v + R[rr * N + cc];
                } else {
                    ((float*)Cout)[(long)blockIdx.z * M * N + rr * N + cc] = v;
                }
            }
}

// ---------------- RMSNorm: one block per row, fp32 in -> bf16 out -------------------
__global__ __launch_bounds__(256) void rmsnorm_kernel(const float* __restrict__ x,
                                                      const float* __restrict__ w,
                                                      bf16* __restrict__ out) {
    const int row = blockIdx.x;
    const int tid = threadIdx.x;
    const float* xr = x + (long)row * HIDDENC;
    float4 a = *(const float4*)&xr[tid * 8];
    float4 b = *(const float4*)&xr[tid * 8 + 4];
    float ss = a.x*a.x + a.y*a.y + a.z*a.z + a.w*a.w + b.x*b.x + b.y*b.y + b.z*b.z + b.w*b.w;
#pragma unroll
    for (int d = 1; d < 64; d <<= 1) ss += __shfl_xor(ss, d, 64);
    __shared__ float wsum[4];
    if ((tid & 63) == 0) wsum[tid >> 6] = ss;
    __syncthreads();
    ss = wsum[0] + wsum[1] + wsum[2] + wsum[3];
    float sc = rsqrtf(ss * (1.0f / HIDDENC) + 1e-6f);
    float4 wa = *(const float4*)&w[tid * 8];
    float4 wb = *(const float4*)&w[tid * 8 + 4];
    float vals[8] = {a.x*wa.x, a.y*wa.y, a.z*wa.z, a.w*wa.w,
                     b.x*wb.x, b.y*wb.y, b.z*wb.z, b.w*wb.w};
    union { bf16x8 v; unsigned short u[8]; } pk;
#pragma unroll
    for (int e = 0; e < 8; e++) pk.u[e] = bf_bits(vals[e] * sc);
    *(bf16x8*)&out[(long)row * HIDDENC + tid * 8] = pk.v;
}

// ---------------- fp32 -> bf16 convert (weights) ------------------------------------
__global__ __launch_bounds__(256) void cvt_kernel(const float* __restrict__ in,
                                                  bf16* __restrict__ out, long n) {
    long idx = ((long)blockIdx.x * 256 + threadIdx.x) * 8;
    if (idx >= n) return;
    float4 a = *(const float4*)&in[idx];
    float4 b = *(const float4*)&in[idx + 4];
    float vals[8] = {a.x, a.y, a.z, a.w, b.x, b.y, b.z, b.w};
    union { bf16x8 v; unsigned short u[8]; } pk;
#pragma unroll
    for (int e = 0; e < 8; e++) pk.u[e] = bf_bits(vals[e]);
    *(bf16x8*)&out[idx] = pk.v;
}

// ---------------- RoPE in-place on bf16 [S][rowstride], heads at col h*HD -----------
__global__ __launch_bounds__(256) void rope_kernel(bf16* __restrict__ x,
                                                   const int* __restrict__ pos,
                                                   int nheads, int rowstride) {
    long gid = (long)blockIdx.x * 256 + threadIdx.x;
    int i = gid & 63;
    long t = gid >> 6;
    int h = (int)(t % nheads);
    long s = t / nheads;
    if (s >= SLEN) return;
    float inv = __expf(-(float)i * 0.14391156516779195f);   // ln(10000)/64
    float f = (float)pos[s] * inv;
    float sn, c;
    sincosf(f, &sn, &c);
    bf16* p = x + s * (long)rowstride + h * HD + i;
    float x1 = __bfloat162float(p[0]);
    float x2 = __bfloat162float(p[64]);
    p[0]  = __float2bfloat16(x1 * c - x2 * sn);
    p[64] = __float2bfloat16(x2 * c + x1 * sn);
}

// ---------------- causal flash attention v2 -----------------------------------------
// grid (32 qtiles, 16 heads) = 512 blocks; qt = 31-bx (heavy first). BQ=64: 4 waves x
// 16 q-rows. K read direct from global (L1/L2); V^T + P in LDS (padded, conflict-free).
__global__ __launch_bounds__(256) void flash_attn(const bf16* __restrict__ Q,   // [S][3072]
                                                  const bf16* __restrict__ Kb,  // +2048 col
                                                  const bf16* __restrict__ Vb,  // +2560 col
                                                  bf16* __restrict__ Ctx) {     // [S][2048]
    constexpr int QSTR = 3072, PSTR = 72, BKEY = 64;
    __shared__ bf16 VT[HD * PSTR];                  // [128 d][64 keys + pad]
    __shared__ bf16 Ps[4][16 * PSTR];               // per-wave P [16 q][64 keys + pad]
    const int qt  = 31 - blockIdx.x;                // heavy tiles dispatched first
    const int h   = blockIdx.y;
    const int kvh = h >> 2;
    const int tid = threadIdx.x;
    const int wave = tid >> 6, lane = tid & 63;
    const int quad = lane >> 4, lrow = lane & 15;
    const int qbase = qt * 64 + wave * 16;

    // resident Q fragments (A-layout: m=lane&15, k=quad*8+e)
    bf16x8 qf[4];
#pragma unroll
    for (int kk = 0; kk < 4; kk++)
        qf[kk] = *(const bf16x8*)&Q[(long)(qbase + lrow) * QSTR + h * HD + kk * 32 + quad * 8];

    f32x4 o[8] = {};
    float mrow[4], lsum[4];
#pragma unroll
    for (int r = 0; r < 4; r++) { mrow[r] = -1e30f; lsum[r] = 0.0f; }

    const int nkt = qt + 1;                         // keys < (qt+1)*64
    const float scale = 0.08838834764831845f;       // 1/sqrt(128)

    for (int kt = 0; kt < nkt; kt++) {
        __syncthreads();                            // VT reuse guard
        // stage V^T [d][key] via VGPR transpose (padded stride)
#pragma unroll
        for (int t = 0; t < 4; t++) {
            int c = t * 256 + tid;
            int key = c >> 4, dc = c & 15;
            bf16x8 vv = *(const bf16x8*)&Vb[(long)(kt * BKEY + key) * QSTR + kvh * HD + dc * 8];
            const short* vs = (const short*)&vv;
#pragma unroll
            for (int e = 0; e < 8; e++)
                *(short*)&VT[(dc * 8 + e) * PSTR + key] = vs[e];
        }
        __syncthreads();

        // S = Q K^T : j(4) key sub-tiles, contraction d=128 (4 kk-steps), K from global
        f32x4 sacc[4] = {};
#pragma unroll
        for (int kk = 0; kk < 4; kk++) {
            bf16x8 kb[4];
#pragma unroll
            for (int j = 0; j < 4; j++)
                kb[j] = *(const bf16x8*)&Kb[(long)(kt * BKEY + j * 16 + lrow) * QSTR + kvh * HD + kk * 32 + quad * 8];
#pragma unroll
            for (int j = 0; j < 4; j++)
                sacc[j] = __builtin_amdgcn_mfma_f32_16x16x32_bf16(qf[kk], kb[j], sacc[j], 0, 0, 0);
        }

        // scale + causal mask (only the diagonal tile kt==qt needs masking)
        const bool diag = (kt == qt);
#pragma unroll
        for (int j = 0; j < 4; j++)
#pragma unroll
            for (int r = 0; r < 4; r++) {
                float v = sacc[j][r] * scale;
                if (diag) {
                    int rowg = qbase + quad * 4 + r;          // global q row
                    int colg = qt * 64 + j * 16 + lrow;       // global key
                    if (colg > rowg) v = -1e30f;
                }
                sacc[j][r] = v;
            }

        // online softmax per q-row (row lives on 16 lanes sharing quad)
        float alpha[4];
#pragma unroll
        for (int r = 0; r < 4; r++) {
            float mx = sacc[0][r];
#pragma unroll
            for (int j = 1; j < 4; j++) mx = fmaxf(mx, sacc[j][r]);
#pragma unroll
            for (int d = 1; d < 16; d <<= 1) mx = fmaxf(mx, __shfl_xor(mx, d, 16));
            float mnew = fmaxf(mrow[r], mx);
            float a = __expf(mrow[r] - mnew);
            mrow[r] = mnew;
            alpha[r] = a;
            float rs = 0.0f;
#pragma unroll
            for (int j = 0; j < 4; j++) {
                float p = __expf(sacc[j][r] - mnew);
                sacc[j][r] = p;
                rs += p;
            }
#pragma unroll
            for (int d = 1; d < 16; d <<= 1) rs += __shfl_xor(rs, d, 16);
            lsum[r] = lsum[r] * a + rs;
        }

        // rescale O
#pragma unroll
        for (int dj = 0; dj < 8; dj++)
#pragma unroll
            for (int r = 0; r < 4; r++) o[dj][r] *= alpha[r];

        // P (C-layout) -> per-wave LDS -> A-operand fragments
        bf16* Pw = Ps[wave];
#pragma unroll
        for (int j = 0; j < 4; j++)
#pragma unroll
            for (int r = 0; r < 4; r++)
                Pw[(quad * 4 + r) * PSTR + j * 16 + lrow] = __float2bfloat16(sacc[j][r]);
        __asm__ volatile("s_waitcnt lgkmcnt(0)" ::: "memory");   // same-wave write->read

        // O += P V  (contraction keys=64: 2 kk-steps)
#pragma unroll
        for (int kk = 0; kk < 2; kk++) {
            bf16x8 pf = *(const bf16x8*)&Pw[lrow * PSTR + kk * 32 + quad * 8];
#pragma unroll
            for (int dj = 0; dj < 8; dj++) {
                bf16x8 vb = *(const bf16x8*)&VT[(dj * 16 + lrow) * PSTR + kk * 32 + quad * 8];
                o[dj] = __builtin_amdgcn_mfma_f32_16x16x32_bf16(pf, vb, o[dj], 0, 0, 0);
            }
        }
    }

    // epilogue: ctx[s][h*128 + d] = O / lsum
#pragma unroll
    for (int dj = 0; dj < 8; dj++)
#pragma unroll
        for (int r = 0; r < 4; r++) {
            long rowg = qbase + quad * 4 + r;
            long col  = (long)h * HD + dj * 16 + lrow;
            Ctx[rowg * (NHEADS * HD) + col] = __float2bfloat16(o[dj][r] / lsum[r]);
        }
}

// ---------------- SwiGLU elementwise: act = silu(gate) * up (bf16) ------------------
__global__ __launch_bounds__(256) void silu_mul_kernel(const bf16* __restrict__ g,
                                                       const bf16* __restrict__ u,
                                                       bf16* __restrict__ out, long n) {
    long idx = ((long)blockIdx.x * 256 + threadIdx.x) * 8;
    if (idx >= n) return;
    bf16x8 gv = *(const bf16x8*)&g[idx];
    bf16x8 uv = *(const bf16x8*)&u[idx];
    union { bf16x8 v; unsigned short w[8]; } pk;
#pragma unroll
    for (int e = 0; e < 8; e++) {
        float gf = bits_f(gv[e]);
        float uf = bits_f(uv[e]);
        float s = gf / (1.0f + __expf(-gf));
        pk.w[e] = bf_bits(s * uf);
    }
    *(bf16x8*)&out[idx] = pk.v;
}

// ---------------- split-K reduce: out += p0 + p1 (residual already in out) ----------
__global__ __launch_bounds__(256) void reduce2_kernel(const float* __restrict__ p,
                                                      float* __restrict__ out, long n) {
    long idx = ((long)blockIdx.x * 256 + threadIdx.x) * 4;
    if (idx >= n) return;
    float4 a = *(const float4*)&p[idx];
    float4 b = *(const float4*)&p[idx + n];
    float4 o = *(const float4*)&out[idx];
    o.x += a.x + b.x; o.y += a.y + b.y; o.z += a.z + b.z; o.w += a.w + b.w;
    *(float4*)&out[idx] = o;
}

// ------------------------------------------------------------------------------------
extern "C" void kernel_launch(void* const* d_in, const int* in_sizes, int n_in,
                              void* d_out, int out_size, void* d_ws, size_t ws_size,
                              hipStream_t stream) {
    const float* hidden = (const float*)d_in[0];
    const int*   pos    = (const int*)d_in[2];
    const float* n1w    = (const float*)d_in[3];
    const float* n2w    = (const float*)d_in[4];
    const float* Wq     = (const float*)d_in[5];
    const float* Wk     = (const float*)d_in[6];
    const float* Wv     = (const float*)d_in[7];
    const float* Wo     = (const float*)d_in[8];
    const float* Wg     = (const float*)d_in[9];
    const float* Wu     = (const float*)d_in[10];
    const float* Wd     = (const float*)d_in[11];
    float* out = (float*)d_out;

    char* ws = (char*)d_ws;
    const size_t MB = 1ull << 20;
    // Phase A:
    bf16* h    = (bf16*)(ws + 0);        // 8 MB  (also h2)
    bf16* qkv  = (bf16*)(ws + 8  * MB);  // 12 MB: [2048][3072] = q|k|v
    bf16* ctx  = (bf16*)(ws + 20 * MB);  // 8 MB
    bf16* wqkv = (bf16*)(ws + 28 * MB);  // 12 MB [3072][2048]; reused for wob (8 MB)
    // Phase B (reuses phase-A space once dead):
    bf16*  wg   = (bf16*)(ws + 8   * MB); // 32 MB
    bf16*  wu   = (bf16*)(ws + 40  * MB); // 32 MB
    bf16*  gate = (bf16*)(ws + 72  * MB); // 32 MB (silu writes act in-place)
    bf16*  up   = (bf16*)(ws + 104 * MB); // 32 MB
    bf16*  wd   = (bf16*)(ws + 104 * MB); // 32 MB (reuses up after silu)
    float* pbuf = (float*)(ws + 28 * MB); // 32 MB (2 x 16 MB split-K partials)
    bf16* wob = wqkv;

    // 1) rmsnorm1 -> h
    rmsnorm_kernel<<<dim3(2048), dim3(256), 0, stream>>>(hidden, n1w, h);
    // 2) convert Wq|Wk|Wv into one [3072][2048] bf16 block
    cvt_kernel<<<dim3(2048), dim3(256), 0, stream>>>(Wq, wqkv,                2048L * 2048);
    cvt_kernel<<<dim3(512),  dim3(256), 0, stream>>>(Wk, wqkv + 2048L * 2048, 512L * 2048);
    cvt_kernel<<<dim3(512),  dim3(256), 0, stream>>>(Wv, wqkv + 2560L * 2048, 512L * 2048);
    // 3) fused QKV projection -> qkv [2048][3072]
    gemm_bt<0><<<dim3(24, 16), dim3(256), 0, stream>>>(h, wqkv, qkv, nullptr, 2048, 3072, 2048, 2048);
    // 4) rope on q (cols 0..2047) and k (cols 2048..2559)
    rope_kernel<<<dim3(8192), dim3(256), 0, stream>>>(qkv, pos, NHEADS, 3072);
    rope_kernel<<<dim3(2048), dim3(256), 0, stream>>>(qkv + 2048, pos, NKV, 3072);
    // 5) flash attention -> ctx
    flash_attn<<<dim3(32, 16), dim3(256), 0, stream>>>(qkv, qkv + 2048, qkv + 2560, ctx);
    // 6) Wo projection + residual -> out (fp32)
    cvt_kernel<<<dim3(2048), dim3(256), 0, stream>>>(Wo, wob, 2048L * 2048);
    gemm_bt<1><<<dim3(16, 16), dim3(256), 0, stream>>>(ctx, wob, out, hidden, 2048, 2048, 2048, 2048);
    // 7) rmsnorm2 -> h
    rmsnorm_kernel<<<dim3(2048), dim3(256), 0, stream>>>(out, n2w, h);
    // 8) MLP
    cvt_kernel<<<dim3(8192), dim3(256), 0, stream>>>(Wg, wg, 8192L * 2048);
    cvt_kernel<<<dim3(8192), dim3(256), 0, stream>>>(Wu, wu, 8192L * 2048);
    gemm_bt<0><<<dim3(64, 16), dim3(256), 0, stream>>>(h, wg, gate, nullptr, 2048, 8192, 2048, 2048);
    gemm_bt<0><<<dim3(64, 16), dim3(256), 0, stream>>>(h, wu, up,   nullptr, 2048, 8192, 2048, 2048);
    silu_mul_kernel<<<dim3(8192), dim3(256), 0, stream>>>(gate, up, gate, 2048L * 8192);
    cvt_kernel<<<dim3(8192), dim3(256), 0, stream>>>(Wd, wd, 2048L * 8192);
    // 9) down-proj split-K=2 -> partials, then out += p0 + p1 (out holds residual x)
    gemm_bt<2><<<dim3(16, 16, 2), dim3(256), 0, stream>>>(gate, wd, pbuf, nullptr, 2048, 2048, 4096, 8192);
    reduce2_kernel<<<dim3(4096), dim3(256), 0, stream>>>(pbuf, out, 2048L * 2048);
    (void)in_sizes; (void)n_in; (void)out_size; (void)ws_size;
}